// Round 9
// baseline (50989.334 us; speedup 1.0000x reference)
//
#include <hip/hip_runtime.h>
#include <math.h>

#define HDIM 1024
#define NTAG 256
#define BSZ 128
#define TLEN 50
#define G3 3072
#define NBLK 256
#define NGRP 8

typedef unsigned long long u64;

// ---- static f32 pool, recurrent tensors transposed [k][b] ----
constexpr u64 GX_F  = (u64)TLEN*G3*BSZ;     // gx [t][n][b]
constexpr u64 SEQ_F = (u64)TLEN*HDIM*BSZ;   // [t][k][b]
constexpr u64 HST_F = (u64)HDIM*BSZ;        // h [k][b]
constexpr u64 F_GX  = 0;
constexpr u64 F_OF0 = F_GX + GX_F;
constexpr u64 F_OB0 = F_OF0 + SEQ_F;
constexpr u64 F_ENC = F_OB0 + SEQ_F;
constexpr u64 F_T0  = F_ENC + SEQ_F;
constexpr u64 F_T1  = F_T0 + HST_F;
constexpr u64 F_H0F = F_T1 + HST_F;
constexpr u64 F_H0B = F_H0F + HST_F;
constexpr u64 F_D0A = F_H0B + HST_F;
constexpr u64 F_D0B = F_D0A + HST_F;
constexpr u64 F_D1A = F_D0B + HST_F;
constexpr u64 F_D1B = F_D1A + HST_F;
constexpr u64 F_CTX = F_D1B + HST_F;
constexpr u64 F_CC  = F_CTX + HST_F;
constexpr u64 F_LG  = F_CC + HST_F;                 // logits [v][b]
constexpr u64 F_QP  = F_LG + (u64)NTAG*BSZ;         // 8 x TLEN x BSZ score partials
constexpr u64 F_A   = F_QP + (u64)8*TLEN*BSZ;       // attn weights [tp][b]
constexpr u64 F_NLL = F_A + (u64)TLEN*BSZ;
constexpr u64 POOL_F= F_NLL + (u64)TLEN*BSZ;

__device__ __align__(256) float g_pool[POOL_F];
__device__ unsigned g_grp[NGRP*32];
__device__ unsigned g_root;
__device__ unsigned g_gen;

__device__ __forceinline__ float sigmf(float x){ return 1.f/(1.f+__expf(-x)); }

// two-level tree barrier: 8 padded group counters + root
__device__ __forceinline__ void grid_sync(){
  __syncthreads();
  if (threadIdx.x == 0){
    __threadfence();
    const int g = blockIdx.x & (NGRP-1);
    unsigned gen = __hip_atomic_load(&g_gen, __ATOMIC_RELAXED, __HIP_MEMORY_SCOPE_AGENT);
    unsigned old = __hip_atomic_fetch_add(&g_grp[g*32], 1u, __ATOMIC_ACQ_REL, __HIP_MEMORY_SCOPE_AGENT);
    if (old == (NBLK/NGRP)-1){
      unsigned ro = __hip_atomic_fetch_add(&g_root, 1u, __ATOMIC_ACQ_REL, __HIP_MEMORY_SCOPE_AGENT);
      if (ro == NGRP-1){
        __hip_atomic_store(&g_root, 0u, __ATOMIC_RELAXED, __HIP_MEMORY_SCOPE_AGENT);
        #pragma unroll
        for (int i=0;i<NGRP;++i)
          __hip_atomic_store(&g_grp[i*32], 0u, __ATOMIC_RELAXED, __HIP_MEMORY_SCOPE_AGENT);
        __hip_atomic_fetch_add(&g_gen, 1u, __ATOMIC_ACQ_REL, __HIP_MEMORY_SCOPE_AGENT);
      } else {
        while (__hip_atomic_load(&g_gen, __ATOMIC_ACQUIRE, __HIP_MEMORY_SCOPE_AGENT) == gen)
          __builtin_amdgcn_s_sleep(2);
      }
    } else {
      while (__hip_atomic_load(&g_gen, __ATOMIC_ACQUIRE, __HIP_MEMORY_SCOPE_AGENT) == gen)
        __builtin_amdgcn_s_sleep(2);
    }
    __threadfence();
  }
  __syncthreads();
}

// full-K GEMM partials: block owns 12 rows (3 gates x 4 j), W in LDS wl[k*12+r],
// k split across 4 waves (256 k each); A read direct from global [k][b].
__device__ __forceinline__ void gemmfk_acc(const float* __restrict__ wl,
                                           const float* __restrict__ aT,
                                           float acc[12][2], int tid)
{
  const int w = tid>>6, l2 = (tid&63)*2;
  #pragma unroll
  for (int r=0;r<12;++r){ acc[r][0]=0.f; acc[r][1]=0.f; }
  const int k0 = w*256;
  for (int k=k0;k<k0+256;++k){
    const float2 a = *(const float2*)&aT[(u64)k*BSZ + l2];
    const float* wr = wl + (u64)k*12;
    float4 w0 = *(const float4*)(wr);
    float4 w1 = *(const float4*)(wr+4);
    float4 w2 = *(const float4*)(wr+8);
    float wv[12]={w0.x,w0.y,w0.z,w0.w,w1.x,w1.y,w1.z,w1.w,w2.x,w2.y,w2.z,w2.w};
    #pragma unroll
    for (int r=0;r<12;++r){ acc[r][0]+=wv[r]*a.x; acc[r][1]+=wv[r]*a.y; }
  }
}

// reduce the 4 wave-partials for b-half (0/1); consumer thread (jj=tid>>6, bb=tid&63)
// gets gh[3] = gates (r,z,n) pre-activations for (j0+jj, b=half*64+bb).
__device__ __forceinline__ void reduce_half(float acc[12][2], float (*red)[12][64],
                                            int half, int tid, float gh[3])
{
  const int w = tid>>6, lane = tid&63;
  const int jj = tid>>6, bb = tid&63;
  __syncthreads();
  if ((lane>>5) == half){
    const int bloc = (lane&31)*2;
    #pragma unroll
    for (int r=0;r<12;++r){ red[w][r][bloc]=acc[r][0]; red[w][r][bloc+1]=acc[r][1]; }
  }
  __syncthreads();
  #pragma unroll
  for (int g=0;g<3;++g){
    float s = red[0][g*4+jj][bb] + red[1][g*4+jj][bb];
    s += red[2][g*4+jj][bb] + red[3][g*4+jj][bb];
    gh[g] = s;
  }
}

#define AM_ENC 0
#define AM_DEC 1
#define AM_CAT 2

// gx[(t*G3+n)*BSZ+b] = A[t,b,:] @ W[n,:]^T + bias[n]  (unchanged)
template<int AMODE>
__global__ __launch_bounds__(256)
void gemm_gx(const float* __restrict__ embed,
             u64 a1_f, u64 a2_f,
             const int* __restrict__ ids,
             const float* __restrict__ W,
             const float* __restrict__ bias,
             u64 c_f, int K)
{
  constexpr int TM=128, TN=64, TK=32;
  __shared__ float As[TK][TM+4];
  __shared__ float Ws[TK][TN+4];
  __shared__ int rowid[TM];
  const int t = blockIdx.x;
  const int n0 = blockIdx.y*TN;
  const int tid = threadIdx.x;

  if (AMODE != AM_CAT){
    for (int r=tid; r<TM; r+=256)
      rowid[r] = (AMODE==AM_ENC) ? ids[r*TLEN+t] : ((t==0)?1:ids[r*TLEN+t-1]);
    __syncthreads();
  }

  const int tm = tid>>4, tn = tid&15;
  float acc[8][4];
  #pragma unroll
  for (int i=0;i<8;i++){ acc[i][0]=0.f;acc[i][1]=0.f;acc[i][2]=0.f;acc[i][3]=0.f; }

  for (int k0=0;k0<K;k0+=TK){
    if (AMODE==AM_CAT){
      const int kk = tid>>3, q = tid&7;
      const int kg = k0 + kk;
      const float* src = g_pool + ((kg<HDIM)? (a1_f + ((u64)t*HDIM + kg)*BSZ)
                                            : (a2_f + ((u64)t*HDIM + (kg-HDIM))*BSZ)) + q*16;
      float* d = &As[kk][q*16];
      float4 v0=*(const float4*)(src+0), v1=*(const float4*)(src+4);
      float4 v2=*(const float4*)(src+8), v3=*(const float4*)(src+12);
      *(float4*)(d+0)=v0; *(float4*)(d+4)=v1; *(float4*)(d+8)=v2; *(float4*)(d+12)=v3;
    } else {
      #pragma unroll
      for (int l=tid; l<TM*TK; l+=256){
        int r=l>>5, k=l&31;
        As[k][r] = embed[(u64)rowid[r]*HDIM + k0 + k];
      }
    }
    #pragma unroll
    for (int l=tid; l<TN*TK; l+=256){
      int n=l>>5, k=l&31;
      Ws[k][n] = W[(u64)(n0+n)*K + k0 + k];
    }
    __syncthreads();
    #pragma unroll 8
    for (int kk=0;kk<TK;kk++){
      float4 a0 = *(const float4*)&As[kk][tm*8];
      float4 a1 = *(const float4*)&As[kk][tm*8+4];
      float4 w  = *(const float4*)&Ws[kk][tn*4];
      float av[8]={a0.x,a0.y,a0.z,a0.w,a1.x,a1.y,a1.z,a1.w};
      float wv[4]={w.x,w.y,w.z,w.w};
      #pragma unroll
      for (int i=0;i<8;i++){
        #pragma unroll
        for (int jj=0;jj<4;jj++) acc[i][jj] += av[i]*wv[jj];
      }
    }
    __syncthreads();
  }

  float bv[4];
  #pragma unroll
  for (int jj=0;jj<4;jj++) bv[jj] = bias[n0+tn*4+jj];
  float* C = g_pool + c_f;
  for (int half=0; half<2; ++half){
    if ((tn>>3)==half){
      #pragma unroll
      for (int i=0;i<8;i++)
        #pragma unroll
        for (int jj=0;jj<4;jj++)
          As[(tn&7)*4+jj][tm*8+i] = acc[i][jj]+bv[jj];
    }
    __syncthreads();
    {
      const int nn = tid>>3, q = tid&7;
      float* dst = C + ((u64)t*G3 + n0 + half*32 + nn)*BSZ + q*16;
      const float* srow = &As[nn][q*16];
      float4 v0=*(const float4*)(srow+0), v1=*(const float4*)(srow+4);
      float4 v2=*(const float4*)(srow+8), v3=*(const float4*)(srow+12);
      *(float4*)(dst+0)=v0; *(float4*)(dst+4)=v1; *(float4*)(dst+8)=v2; *(float4*)(dst+12)=v3;
    }
    __syncthreads();
  }
}

// persistent masked GRU scan: 1 grid barrier per step, full-K, wave k-split
template<bool BWD, bool ACCUM>
__global__ __launch_bounds__(256)
void scan_kernel(u64 gx_f, u64 p0_f, u64 p1_f,
                 const float* __restrict__ whh, const float* __restrict__ bhh,
                 const int* __restrict__ lengths, u64 out_f)
{
  __shared__ __align__(16) float wl[HDIM*12];
  __shared__ __align__(16) float red[4][12][64];
  const int bid = blockIdx.x, tid = threadIdx.x;
  const int j0 = bid*4;
  #pragma unroll
  for (int r=0;r<12;++r){
    const int row = (r>>2)*HDIM + j0 + (r&3);
    for (int k=tid;k<HDIM;k+=256) wl[k*12+r] = whh[(u64)row*HDIM + k];
  }
  __syncthreads();

  const int jj = tid>>6, bb = tid&63;
  const int jg = j0 + jj;
  const float b_r = bhh[jg], b_z = bhh[HDIM+jg], b_n = bhh[2*HDIM+jg];
  const int lenH[2] = { lengths[bb], lengths[bb+64] };

  for (int s=0; s<TLEN; ++s){
    const int t = BWD ? (TLEN-1-s) : s;
    const u64 rd = (s&1)? p0_f : p1_f;
    const u64 wr = (s&1)? p1_f : p0_f;
    float acc[12][2];
    if (s>0) gemmfk_acc(wl, g_pool + rd, acc, tid);
    const float* gxb = g_pool + gx_f + (u64)t*G3*BSZ;
    #pragma unroll
    for (int half=0; half<2; ++half){
      float gh[3] = {0.f,0.f,0.f};
      if (s>0) reduce_half(acc, red, half, tid, gh);
      const int b = half*64 + bb;
      const bool m = (t < lenH[half]);
      const float xr = gxb[(u64)jg*BSZ + b];
      const float xz = gxb[(u64)(HDIM+jg)*BSZ + b];
      const float xn = gxb[(u64)(2*HDIM+jg)*BSZ + b];
      const float hp = (s>0)? g_pool[rd + (u64)jg*BSZ + b] : 0.f;
      const float r = sigmf(xr + gh[0] + b_r);
      const float z = sigmf(xz + gh[1] + b_z);
      const float n = tanhf(xn + r*(gh[2] + b_n));
      const float hv = (1.f-z)*n + z*hp;
      g_pool[wr + (u64)jg*BSZ + b] = m ? hv : hp;
      const u64 oidx = out_f + ((u64)t*HDIM + jg)*BSZ + b;
      if (ACCUM){ if (m) g_pool[oidx] += hv; }
      else g_pool[oidx] = m ? hv : 0.f;
    }
    grid_sync();
  }
}

// persistent decoder: 7 grid barriers per step
__global__ __launch_bounds__(256)
void decoder_kernel(const float* __restrict__ whh0, const float* __restrict__ bhh0,
                    const float* __restrict__ wih1, const float* __restrict__ bih1,
                    const float* __restrict__ whh1, const float* __restrict__ bhh1,
                    const float* __restrict__ cw, const float* __restrict__ cb,
                    const float* __restrict__ ow, const float* __restrict__ ob,
                    const int* __restrict__ tag_ids, const int* __restrict__ lengths,
                    float* __restrict__ dout)
{
  __shared__ __align__(16) float wl0[HDIM*12];
  __shared__ __align__(16) float wl1[HDIM*12];
  __shared__ __align__(16) float wl2[HDIM*12];
  __shared__ __align__(16) float red[4][12][64];
  const int bid = blockIdx.x, tid = threadIdx.x;
  const int j0 = bid*4;
  #pragma unroll
  for (int r=0;r<12;++r){
    const int row = (r>>2)*HDIM + j0 + (r&3);
    for (int k=tid;k<HDIM;k+=256){
      wl0[k*12+r] = whh0[(u64)row*HDIM + k];
      wl1[k*12+r] = wih1[(u64)row*HDIM + k];
      wl2[k*12+r] = whh1[(u64)row*HDIM + k];
    }
  }
  __syncthreads();

  const int w = tid>>6, lane = tid&63;
  const int jj = tid>>6, bb = tid&63;
  const int jg = j0 + jj;
  const int l2 = lane*2;

  for (int t=0; t<TLEN; ++t){
    const u64 h0c = (t==0)? F_H0F : ((t&1)? F_D0A : F_D0B);
    const u64 h0n = (t&1)? F_D0B : F_D0A;
    const u64 h1c = (t==0)? F_H0B : ((t&1)? F_D1A : F_D1B);
    const u64 h1n = (t&1)? F_D1B : F_D1A;

    // ---- P1: layer-0 GRU (full-K, fused gates) ----
    {
      float acc[12][2];
      gemmfk_acc(wl0, g_pool + h0c, acc, tid);
      const float* gxb = g_pool + F_GX + (u64)t*G3*BSZ;
      const float b_r=bhh0[jg], b_z=bhh0[HDIM+jg], b_n=bhh0[2*HDIM+jg];
      #pragma unroll
      for (int half=0; half<2; ++half){
        float gh[3];
        reduce_half(acc, red, half, tid, gh);
        const int b = half*64 + bb;
        const float xr = gxb[(u64)jg*BSZ+b], xz = gxb[(u64)(HDIM+jg)*BSZ+b], xn = gxb[(u64)(2*HDIM+jg)*BSZ+b];
        const float hp = g_pool[h0c + (u64)jg*BSZ + b];
        const float r = sigmf(xr + gh[0] + b_r), z = sigmf(xz + gh[1] + b_z);
        const float n = tanhf(xn + r*(gh[2] + b_n));
        g_pool[h0n + (u64)jg*BSZ + b] = (1.f-z)*n + z*hp;
      }
    }
    grid_sync();   // b1

    // ---- P2: layer-1 GRU (two full-K GEMMs, fused gates) ----
    {
      float acc[12][2];
      float aX0[3], aX1[3], aH0[3], aH1[3];
      gemmfk_acc(wl1, g_pool + h0n, acc, tid);
      reduce_half(acc, red, 0, tid, aX0);
      reduce_half(acc, red, 1, tid, aX1);
      gemmfk_acc(wl2, g_pool + h1c, acc, tid);
      reduce_half(acc, red, 0, tid, aH0);
      reduce_half(acc, red, 1, tid, aH1);
      const float bxr=bih1[jg], bxz=bih1[HDIM+jg], bxn=bih1[2*HDIM+jg];
      const float bhr=bhh1[jg], bhz=bhh1[HDIM+jg], bhn=bhh1[2*HDIM+jg];
      #pragma unroll
      for (int half=0; half<2; ++half){
        const float* aX = half? aX1 : aX0;
        const float* aH = half? aH1 : aH0;
        const int b = half*64 + bb;
        const float hp = g_pool[h1c + (u64)jg*BSZ + b];
        const float r = sigmf(aX[0]+bxr + aH[0]+bhr), z = sigmf(aX[1]+bxz + aH[1]+bhz);
        const float n = tanhf(aX[2]+bxn + r*(aH[2]+bhn));
        g_pool[h1n + (u64)jg*BSZ + b] = (1.f-z)*n + z*hp;
      }
    }
    grid_sync();   // b2

    // ---- P3: score partials (8-way k-split over 200 blocks) ----
    if (bid < 200){
      const int tp = bid>>2, kq = bid&3;
      const int b = tid&127, q2 = tid>>7;
      const int kst = kq*256 + q2*128;
      const float* hT = g_pool + h1n;
      const float* eT = g_pool + F_ENC + (u64)tp*HDIM*BSZ;
      float a0=0.f,a1=0.f;
      for (int k=kst;k<kst+128;k+=2){
        a0 += hT[(u64)k*BSZ+b]     * eT[(u64)k*BSZ+b];
        a1 += hT[(u64)(k+1)*BSZ+b] * eT[(u64)(k+1)*BSZ+b];
      }
      g_pool[F_QP + (u64)(kq*2+q2)*TLEN*BSZ + (u64)tp*BSZ + b] = a0+a1;
    }
    grid_sync();   // b3

    // ---- P4a: softmax over tp ----
    if (bid < BSZ && tid < 64){
      const int b = bid;
      float v = -1e30f;
      if (tid < TLEN){
        v = 0.f;
        #pragma unroll
        for (int q=0;q<8;++q) v += g_pool[F_QP + (u64)q*TLEN*BSZ + (u64)tid*BSZ + b];
      }
      float mx = v;
      #pragma unroll
      for (int o=32;o;o>>=1) mx = fmaxf(mx, __shfl_xor(mx,o));
      float e = (tid<TLEN)? __expf(v-mx) : 0.f;
      float sm = e;
      #pragma unroll
      for (int o=32;o;o>>=1) sm += __shfl_xor(sm,o);
      if (tid < TLEN) g_pool[F_A + (u64)tid*BSZ + b] = e/sm;
    }
    grid_sync();   // b4

    // ---- P4b: ctx[k][b] ----
    {
      const int b = tid&127, rh = tid>>7;
      #pragma unroll
      for (int r2=0;r2<2;++r2){
        const int k = bid*4 + rh + 2*r2;
        float acc = 0.f;
        #pragma unroll 5
        for (int tp=0;tp<TLEN;++tp)
          acc += g_pool[F_A + (u64)tp*BSZ + b] * g_pool[F_ENC + ((u64)tp*HDIM + k)*BSZ + b];
        g_pool[F_CTX + (u64)k*BSZ + b] = acc;
      }
    }
    grid_sync();   // b5

    // ---- P5: cc rows n0..n0+3 over K=2048, wave k-split 512 ----
    {
      const int n0 = bid*4;
      float acc4[4][2] = {{0,0},{0,0},{0,0},{0,0}};
      const int k0 = w*512;
      const float* Abase = (k0<1024)? (g_pool + h1n) : (g_pool + F_CTX - (u64)1024*BSZ);
      for (int k=k0;k<k0+512;++k){
        const float2 a = *(const float2*)&Abase[(u64)k*BSZ + l2];
        float wv[4];
        #pragma unroll
        for (int r=0;r<4;++r) wv[r] = cw[(u64)(n0+r)*(2*HDIM) + k];
        #pragma unroll
        for (int r=0;r<4;++r){ acc4[r][0]+=wv[r]*a.x; acc4[r][1]+=wv[r]*a.y; }
      }
      #pragma unroll
      for (int half=0; half<2; ++half){
        __syncthreads();
        if ((lane>>5) == half){
          const int bloc = (lane&31)*2;
          #pragma unroll
          for (int r=0;r<4;++r){ red[w][r][bloc]=acc4[r][0]; red[w][r][bloc+1]=acc4[r][1]; }
        }
        __syncthreads();
        const int rr = tid>>6;
        float s = cb[n0+rr];
        #pragma unroll
        for (int ww=0;ww<4;++ww) s += red[ww][rr][bb];
        g_pool[F_CC + (u64)(n0+rr)*BSZ + half*64 + bb] = tanhf(s);
      }
    }
    grid_sync();   // b6

    // ---- P6: logits row v=bid over K=1024, wave k-split 256 ----
    {
      float a0=0.f, a1=0.f;
      const float* owv = ow + (u64)bid*HDIM;
      const float* ccb = g_pool + F_CC;
      const int k0 = w*256;
      for (int k=k0;k<k0+256;++k){
        const float wv = owv[k];
        const float2 a = *(const float2*)&ccb[(u64)k*BSZ + l2];
        a0 += wv*a.x; a1 += wv*a.y;
      }
      float* red2 = (float*)red;
      __syncthreads();
      red2[w*128 + l2] = a0; red2[w*128 + l2 + 1] = a1;
      __syncthreads();
      if (tid < 128){
        float lg = ob[bid];
        #pragma unroll
        for (int ww=0;ww<4;++ww) lg += red2[ww*128 + tid];
        g_pool[F_LG + (u64)bid*BSZ + tid] = lg;
      }
    }
    grid_sync();   // b7

    // ---- P7: per-b softmax, write dout + nll ----
    if (bid < BSZ){
      float* lgs = (float*)red;
      float* rp  = ((float*)red) + 256;
      const int b = bid, v = tid;
      const float lg = g_pool[F_LG + (u64)v*BSZ + b];
      lgs[v] = lg; rp[v] = lg;
      __syncthreads();
      for (int o=128;o;o>>=1){ if (tid<o) rp[tid]=fmaxf(rp[tid],rp[tid+o]); __syncthreads(); }
      const float mx = rp[0];
      __syncthreads();
      rp[tid] = __expf(lg-mx);
      __syncthreads();
      for (int o=128;o;o>>=1){ if (tid<o) rp[tid]+=rp[tid+o]; __syncthreads(); }
      const float lse = mx + __logf(rp[0]);
      dout[((u64)b*TLEN + t)*NTAG + v] = lg;
      if (tid==0){
        const int tag = tag_ids[b*TLEN + t];
        g_pool[F_NLL + (u64)t*BSZ + b] = lse - lgs[tag];
      }
    }
    // no trailing barrier (next P1 touches disjoint buffers; b1 orders it)
  }
  grid_sync();
  // ---- loss ----
  if (bid == 0){
    float* rp = (float*)red;
    float ssum = 0.f;
    for (int i=tid; i<TLEN*BSZ; i+=256){
      const int tt = i>>7, b = i&127;
      if (tt < lengths[b]) ssum += g_pool[F_NLL + i];
    }
    rp[tid] = ssum; __syncthreads();
    for (int o=128;o;o>>=1){ if (tid<o) rp[tid]+=rp[tid+o]; __syncthreads(); }
    if (tid==0){
      int den=0;
      for (int b=0;b<BSZ;b++) den += lengths[b];
      dout[(u64)BSZ*TLEN*NTAG] = rp[0]/(float)den;
    }
  }
}

extern "C" void kernel_launch(void* const* d_in, const int* in_sizes, int n_in,
                              void* d_out, int out_size, void* d_ws, size_t ws_size,
                              hipStream_t stream)
{
  const float* enc_embed = (const float*)d_in[0];
  const float* e0_wih = (const float*)d_in[1];
  const float* e0_whh = (const float*)d_in[2];
  const float* e0_bih = (const float*)d_in[3];
  const float* e0_bhh = (const float*)d_in[4];
  const float* e1_wih = (const float*)d_in[5];
  const float* e1_whh = (const float*)d_in[6];
  const float* e1_bih = (const float*)d_in[7];
  const float* e1_bhh = (const float*)d_in[8];
  const float* dec_embed = (const float*)d_in[9];
  const float* d_wih = (const float*)d_in[10];
  const float* d_whh = (const float*)d_in[11];
  const float* d_bih = (const float*)d_in[12];
  const float* d_bhh = (const float*)d_in[13];
  const float* concat_w = (const float*)d_in[14];
  const float* concat_b = (const float*)d_in[15];
  const float* out_w = (const float*)d_in[16];
  const float* out_b = (const float*)d_in[17];
  const int* input_ids = (const int*)d_in[18];
  const int* tag_ids  = (const int*)d_in[19];
  const int* lengths  = (const int*)d_in[20];
  float* dout = (float*)d_out;

  const dim3 gxg(TLEN, G3/64);

  // encoder L0 fwd
  gemm_gx<AM_ENC><<<gxg,256,0,stream>>>(enc_embed,0,0,input_ids,e0_wih,e0_bih,F_GX,HDIM);
  scan_kernel<false,false><<<NBLK,256,0,stream>>>(F_GX, F_T0, F_H0F, e0_whh, e0_bhh, lengths, F_OF0);
  // encoder L0 bwd
  gemm_gx<AM_ENC><<<gxg,256,0,stream>>>(enc_embed,0,0,input_ids,
                                        e0_wih+(u64)G3*HDIM, e0_bih+G3, F_GX, HDIM);
  scan_kernel<true,false><<<NBLK,256,0,stream>>>(F_GX, F_T0, F_H0B,
                                        e0_whh+(u64)G3*HDIM, e0_bhh+G3, lengths, F_OB0);
  // encoder L1 fwd
  gemm_gx<AM_CAT><<<gxg,256,0,stream>>>(nullptr, F_OF0, F_OB0, nullptr,
                                        e1_wih, e1_bih, F_GX, 2*HDIM);
  scan_kernel<false,false><<<NBLK,256,0,stream>>>(F_GX, F_T0, F_T1, e1_whh, e1_bhh, lengths, F_ENC);
  // encoder L1 bwd (accumulate)
  gemm_gx<AM_CAT><<<gxg,256,0,stream>>>(nullptr, F_OF0, F_OB0, nullptr,
                                        e1_wih+(u64)G3*2*HDIM, e1_bih+G3, F_GX, 2*HDIM);
  scan_kernel<true,true><<<NBLK,256,0,stream>>>(F_GX, F_T0, F_T1,
                                        e1_whh+(u64)G3*HDIM, e1_bhh+G3, lengths, F_ENC);
  // decoder
  gemm_gx<AM_DEC><<<gxg,256,0,stream>>>(dec_embed,0,0,tag_ids, d_wih, d_bih, F_GX, HDIM);
  decoder_kernel<<<NBLK,256,0,stream>>>(d_whh, d_bhh,
                                        d_wih+(u64)G3*HDIM, d_bih+G3,
                                        d_whh+(u64)G3*HDIM, d_bhh+G3,
                                        concat_w, concat_b, out_w, out_b,
                                        tag_ids, lengths, dout);
}